// Round 13
// baseline (617.457 us; speedup 1.0000x reference)
//
#include <hip/hip_runtime.h>
#include <hip/hip_bf16.h>

#define N 1024
#define D 128
#define SB 8           // steps per superstep (gi chunk staged in LDS)
#define NSB (N / SB)
#define QK_NC 32       // c-chunk for LDS-staged qk weights

typedef __hip_bfloat16 bf16;
typedef __attribute__((ext_vector_type(8))) short bfx8;    // 8 bf16 (4 VGPRs) MFMA A/B frag
typedef __attribute__((ext_vector_type(4))) float fx4;     // MFMA C/D frag
typedef __attribute__((ext_vector_type(4))) unsigned short u16x4;

__device__ __forceinline__ float b2f(bf16 x) { return __bfloat162float(x); }
__device__ __forceinline__ short f2bf_bits(float x) {
    bf16 b = __float2bfloat16(x);
    return *reinterpret_cast<short*>(&b);
}
__device__ __forceinline__ float bfbits2f(unsigned short u) {
    return __uint_as_float(((unsigned int)u) << 16);
}
__device__ __forceinline__ float fastrcp(float x) { return __builtin_amdgcn_rcpf(x); }

__device__ __forceinline__ float fast_tanh(float x) {
    float e = __expf(2.f * x);
    return 1.f - 2.f * fastrcp(e + 1.f);
}
__device__ __forceinline__ float fast_sigmoid(float x) {
    return fastrcp(1.f + __expf(-x));
}

// dynamic extract from fx4 by r (3 cndmask)
__device__ __forceinline__ float sel4(fx4 v, int r) {
    float x = (r & 1) ? v[1] : v[0];
    float y = (r & 1) ? v[3] : v[2];
    return (r & 2) ? y : x;
}

// async 16B global->LDS (lds base wave-uniform; HW scatters lane i at base+i*16)
__device__ __forceinline__ void async_copy16(const float* g, void* l) {
    __builtin_amdgcn_global_load_lds((const __attribute__((address_space(1))) void*)g,
                                     (__attribute__((address_space(3))) void*)l, 16, 0, 0);
}

// consumer-side: wait until all 8 rows of 8-row group grp are published.
// SPIN-SAFETY (r6/r8 lessons): the ONLY spinner in the whole pipeline is the single GRU
// block; producer blocks never wait on anything (retire-per-unit). No global barriers.
__device__ __forceinline__ void wait_rows(int* cnt, int grp) {
    while (__hip_atomic_load(&cnt[grp], __ATOMIC_ACQUIRE, __HIP_MEMORY_SCOPE_AGENT) < 8)
        __builtin_amdgcn_s_sleep(2);
}

__device__ __forceinline__ float cvt(const void* p, int idx, int isbf) {
    return isbf ? b2f(((const bf16*)p)[idx]) : ((const float*)p)[idx];
}

#define MFMA(A, B, C) __builtin_amdgcn_mfma_f32_16x16x32_bf16((A), (B), (C), 0, 0, 0)

// ---------------- K1: merged qk + prep (1604 blocks, zero cross-block deps) ------------
// Blocks 0..1023 (qk role): sniff, convert X row i, compute q[i,:]/kT[:,i] by staging
// raw Wq/Wk c-chunks into LDS TRANSPOSED (coalesced global reads; pad-129 rows ->
// conflict-free LDS writes AND reads). No dependency on prep blocks.
// Blocks 1024..1603 (prep role): sniff + one 256-elem slab of {v, wihT (c-major, full),
// whh, bih, bhh} conversions. Block 0 inits flag/cnt/rcnt.
// gix is GONE: fused Phase D now does the x-half MACs too (finisher-only, cheap).
__global__ void __launch_bounds__(256) qkprep_kernel(
        const void* inX, const void* inWq, const void* inWk, const void* inV,
        const void* inWih, const void* inWhh, const void* inBih, const void* inBhh,
        float* __restrict__ Xf, float* __restrict__ q, float* __restrict__ kT,
        float* __restrict__ vf, float* __restrict__ wihT, float* __restrict__ whhf,
        float* __restrict__ bihf, float* __restrict__ bhhf,
        int* __restrict__ flag, int* __restrict__ cnt, int* __restrict__ rcnt) {
    __shared__ float xs[D];
    __shared__ int red[256];
    __shared__ float stg[2][QK_NC][129];   // 33 KB: [Wq|Wk][cc][d], pad-129 rows
    int bid = blockIdx.x, t = threadIdx.x;

    // self-sniff (same 1024 samples every block -> identical decision)
    const unsigned short* xu = (const unsigned short*)inX;
    int c = 0;
#pragma unroll
    for (int k = 0; k < 4; ++k) {
        unsigned short u = xu[2 * (4 * t + k)];
        int e = (u >> 7) & 0xFF;
        c += (e >= 96 && e <= 144) ? 1 : 0;
    }
    red[t] = c;
    __syncthreads();
    for (int st = 128; st > 0; st >>= 1) {
        if (t < st) red[t] += red[t + st];
        __syncthreads();
    }
    int isbf = red[0] > 800;

    if (bid == 0) {
        if (t == 0) *flag = isbf;
        if (t < 128) { cnt[t] = 0; rcnt[t] = 0; }
    }

    if (bid < 1024) {
        // ============ qk role: row i ============
        int i = bid;
        if (t < D) {
            float xv = cvt(inX, i * D + t, isbf);
            xs[t] = xv;
            Xf[i * D + t] = xv;
        }
        __syncthreads();
        int d = t & 127;
        float acc = 0.f;
        for (int c0 = 0; c0 < D; c0 += QK_NC) {
            // stage: 2 * 128 * 32 = 8192 elems, 32/thread; global reads run over
            // 32-consecutive-c segments of each weight row (coalesced in 64-128B runs);
            // LDS writes stg[w][cc][dd]: lanes sweep cc with stride-129 rows -> all banks.
            for (int e = t; e < 2 * 128 * QK_NC; e += 256) {
                int w = e >> 12;
                int r = e & 4095;
                int dd = r >> 5;
                int cc = r & 31;
                stg[w][cc][dd] = cvt(w ? inWk : inWq, dd * D + c0 + cc, isbf);
            }
            __syncthreads();
            const float (*S)[129] = (t < 128) ? stg[0] : stg[1];
#pragma unroll
            for (int cc = 0; cc < QK_NC; ++cc) acc += xs[c0 + cc] * S[cc][d];
            __syncthreads();
        }
        if (t < 128) q[i * D + d] = acc;
        else         kT[d * N + i] = acc;
    } else {
        // ============ prep role: one 256-elem slab ============
        int id = (bid - 1024) * 256 + t;
        if (id < 128) {
            vf[id] = cvt(inV, id, isbf);
        } else if (id < 98432) {
            int k = id - 128; int cc = k / 384, o = k - cc * 384;
            wihT[k] = cvt(inWih, o * 256 + cc, isbf);     // full c-major [256][384]
        } else if (id < 147584) {
            whhf[id - 98432] = cvt(inWhh, id - 98432, isbf);
        } else if (id < 147968) {
            bihf[id - 147584] = cvt(inBih, id - 147584, isbf);
        } else if (id < 148352) {
            bhhf[id - 147968] = cvt(inBhh, id - 147968, isbf);
        }
    }
}

// ---------------- K2: fused producer/consumer ----------------
// block 0: GRU (setprio 2, r12-exact body — measured 471us). blocks 1..256: rows 0-31
// split 8-way; 257..448: rows 32-127 split 2-way; 449..1344: rows 128-1023 whole.
// Split parts write online-softmax partials (m,S,A); last-arriver combines + Phase D
// (BOTH wih halves: x-part from xr, att-part from al — gix eliminated) + publishes
// cnt[row/8]. LDS union: GRU 26880 B; attn 7168 B.
// Phase A/B static 4-iter unrolls (sj in registers — rule #20; r12: −30% attn wave-time).
// NOTE: do NOT set a min-waves launch bound — capping VGPRs below ~130 spills the GRU's
// 96 resident weight VGPRs to scratch (round-3 catastrophe: 617 -> 1676 us).
__global__ void __launch_bounds__(256, 1) fused_kernel(
        const float* __restrict__ q, const float* __restrict__ kT,
        const float* __restrict__ v, const float* __restrict__ X,
        const float* __restrict__ wihT, const float* __restrict__ b_ih,
        const float* __restrict__ b_hh,
        float* __restrict__ gi, const float* __restrict__ w_hh,
        void* __restrict__ out, const int* __restrict__ flag,
        int* __restrict__ cnt, int* __restrict__ rcnt,
        float* __restrict__ attMS, float* __restrict__ attA) {
    __shared__ __align__(16) char smem[2 * SB * 3 * D * 4 + (SB + 1) * D * 2];  // 26880 B
    int t = threadIdx.x;

    if (blockIdx.x != 0) {
        // =================== attention row (full or partial) ===================
        int b = blockIdx.x - 1;
        int i, P, p;
        if (b < 256)      { i = b >> 3;            P = 8; p = b & 7; }
        else if (b < 448) { int e = b - 256; i = 32 + (e >> 1); P = 2; p = e & 1; }
        else              { i = 128 + (b - 448);   P = 1; p = 0; }

        float* qs   = (float*)smem;        // D
        float* vs   = qs + D;              // D
        float* xr   = vs + D;              // D
        float* al   = xr + D;              // D
        float* wrow = al + D;              // up to 1024
        float* red  = wrow + N;            // 256

        int len = (N - i + P - 1) / P;
        int j0 = i + p * len;
        int j1 = min(j0 + len, N);

        if (t < D) { qs[t] = q[i * D + t]; vs[t] = v[t]; xr[t] = X[i * D + t]; }
        __syncthreads();

        // Phase A: scores over [j0, j1) — static 4-iter unroll (sj in registers,
        // 4 independent kT-load/tanh streams in flight). Max chunk 896 -> 4 iters cover.
        float sj[4];
        float m = -1e30f;
#pragma unroll
        for (int it = 0; it < 4; ++it) {
            int j = j0 + t + it * 256;
            float s = -1e30f;
            if (j < j1) {
                s = 0.f;
#pragma unroll 8
                for (int dd = 0; dd < D; ++dd)
                    s += vs[dd] * fast_tanh(qs[dd] + kT[dd * N + j]);
            }
            sj[it] = s;
            m = fmaxf(m, s);
        }
        red[t] = m;
        __syncthreads();
        for (int st = 128; st > 0; st >>= 1) {
            if (t < st) red[t] = fmaxf(red[t], red[t + st]);
            __syncthreads();
        }
        m = red[0];
        __syncthreads();
        // Phase B: exp + local sum (same static indexing)
        float lsum = 0.f;
#pragma unroll
        for (int it = 0; it < 4; ++it) {
            int j = j0 + t + it * 256;
            if (j < j1) {
                float pe = __expf(sj[it] - m);
                wrow[j - j0] = pe;
                lsum += pe;
            }
        }
        red[t] = lsum;
        __syncthreads();
        for (int st = 128; st > 0; st >>= 1) {
            if (t < st) red[t] += red[t + st];
            __syncthreads();
        }
        float S = red[0];
        __syncthreads();
        // Phase C: unnormalized A[d] over chunk (2-way j split); unroll 4 for load ILP
        int d = t & 127, half = t >> 7;
        float acc = 0.f;
        int cl = j1 - j0;
#pragma unroll 4
        for (int jj = half; jj < cl; jj += 2) acc += wrow[jj] * X[(j0 + jj) * D + d];
        if (half) red[d] = acc;
        __syncthreads();
        if (!half) al[d] = acc + red[d];
        __syncthreads();

        if (P > 1) {
            // write partials, last-arriver combines
            if (t < D) attA[(i * 8 + p) * D + t] = al[t];
            if (t == 0) { attMS[(i * 8 + p) * 2] = m; attMS[(i * 8 + p) * 2 + 1] = S; }
            __syncthreads();
            if (t == 0) {
                __threadfence();
                int arr = __hip_atomic_fetch_add(&rcnt[i], 1, __ATOMIC_ACQ_REL,
                                                 __HIP_MEMORY_SCOPE_AGENT);
                ((int*)red)[0] = arr;
            }
            __syncthreads();
            int arr = ((int*)red)[0];
            if (arr != P - 1) return;   // uniform per block
            // finisher: combine partials
            if (t < D) {
                float M = -1e30f;
                for (int pp = 0; pp < P; ++pp) M = fmaxf(M, attMS[(i * 8 + pp) * 2]);
                float Ssum = 0.f, av = 0.f;
                for (int pp = 0; pp < P; ++pp) {
                    float wp = __expf(attMS[(i * 8 + pp) * 2] - M);
                    Ssum += attMS[(i * 8 + pp) * 2 + 1] * wp;
                    av += attA[(i * 8 + pp) * D + t] * wp;
                }
                al[t] = av * fastrcp(Ssum);
            }
            __syncthreads();
        } else {
            float inv = fastrcp(S);
            if (t < D) al[t] *= inv;
            __syncthreads();
        }

        // Phase D: BOTH halves (x-part from xr, att-part from al); fold b_hh for r,z.
        // wihT is full c-major [256][384] -> wt[cc*384] coalesced across o.
        for (int o = t; o < 3 * D; o += 256) {
            float a2 = b_ih[o] + ((o < 2 * D) ? b_hh[o] : 0.f);
            const float* wtx = wihT + o;               // x-half cols 0..127
            const float* wta = wihT + 128 * 384 + o;   // att-half cols 128..255
#pragma unroll 8
            for (int cc = 0; cc < D; ++cc) a2 += xr[cc] * wtx[cc * 384];
#pragma unroll 8
            for (int cc = 0; cc < D; ++cc) a2 += al[cc] * wta[cc * 384];
            gi[i * 3 * D + o] = a2;
        }
        __syncthreads();
        if (t == 0) {
            __threadfence();
            __hip_atomic_fetch_add(&cnt[i >> 3], 1, __ATOMIC_RELEASE, __HIP_MEMORY_SCOPE_AGENT);
        }
        return;
    }

    // =================== GRU (1 block, serial over N steps — r12-exact) ===================
    __builtin_amdgcn_s_setprio(2);
    float* gi_lds = (float*)smem;                           // [2][SB][3D]
    short* hist   = (short*)(smem + 2 * SB * 3 * D * 4);    // [SB+1][D]
    int w = t >> 6;
    int l = t & 63;
    int qq = l >> 4;
    int nn = l & 15;
    int isbf = *flag;

    // A-frags: a[tau][mqi][kc]; A[m=nn][k=32kc+8q+j]  (96 resident VGPRs — must NOT spill)
    bfx8 a[3][2][4];
#pragma unroll
    for (int tau = 0; tau < 3; ++tau)
#pragma unroll
        for (int mqi = 0; mqi < 2; ++mqi)
#pragma unroll
            for (int kc = 0; kc < 4; ++kc) {
                int row = 128 * tau + 16 * (2 * w + mqi) + nn;
                int k0 = 32 * kc + 8 * qq;
#pragma unroll
                for (int j = 0; j < 8; ++j)
                    a[tau][mqi][kc][j] = f2bf_bits(w_hh[row * D + k0 + j]);
            }
    // n-gate bias only (r,z biases folded into gi by the producer)
    fx4 bias2[2];
#pragma unroll
    for (int mqi = 0; mqi < 2; ++mqi)
#pragma unroll
        for (int r = 0; r < 4; ++r)
            bias2[mqi][r] = b_hh[2 * D + 16 * (2 * w + mqi) + 4 * qq + r];
    const fx4 zed = {0.f, 0.f, 0.f, 0.f};

    int rsel = l & 3;
    int mqsel = (l >> 3) & 1;
    int drow = 32 * w + 16 * mqsel + 4 * qq + rsel;
    float h = 0.f;

    int fr = 1 + (t >> 5);      // 1..8
    int fc = (t & 31) * 4;      // 0..124

    // wait for first 8 rows, prime superstep-0 staging (3 copies/wave)
    wait_rows(cnt, 0);
    {
        const float* src = gi;
        for (int mm = 0; mm < 3; ++mm) {
            int off = (w * 3 + mm) * 256;
            async_copy16(src + off + (l << 2), smem + off * 4);
        }
    }

    for (int sb = 0; sb < NSB; ++sb) {
        int cb = sb & 1;
        u16x4 hv = {0, 0, 0, 0};
        int hcopy = 0;
        if (sb > 0) {
            hv = *(const u16x4*)(hist + fr * D + fc);
            if (t < 64) hcopy = ((const int*)(hist + SB * D))[t];
        }
        // prefetch sb+1 FIRST (counted vmcnt leaves stores in flight)
        if (sb + 1 < NSB) {
            wait_rows(cnt, sb + 1);
            const float* src = gi + (size_t)(sb + 1) * SB * 3 * D;
            char* dst = smem + (cb ^ 1) * SB * 3 * D * 4;
            for (int mm = 0; mm < 3; ++mm) {
                int off = (w * 3 + mm) * 256;
                async_copy16(src + off + (l << 2), dst + off * 4);
            }
        }
        // output stores for superstep sb-1 (1 store/thread)
        if (sb > 0) {
            int orow = (sb - 1) * SB + fr - 1;
            if (isbf) {
                *(u16x4*)((unsigned short*)out + orow * D + fc) = hv;
            } else {
                float* op = (float*)out + orow * D + fc;
                fx4 f0;
#pragma unroll
                for (int j = 0; j < 4; ++j) f0[j] = bfbits2f(hv[j]);
                *(fx4*)op = f0;
            }
        }
        if (t < 64) ((int*)hist)[t] = (sb == 0) ? 0 : hcopy;

        // Counted vmcnt (in-order retirement); pf=3 copies, st=1 store per thread:
        //   sb==0: newer-than-pf(0) = pf(1)=3             -> vmcnt(3)
        //   sb==1: newer-than-pf(1) = pf(2)+st = 4        -> vmcnt(4)
        //   mid:   newer-than-pf(sb) = st+pf+st = 5       -> vmcnt(5)
        //   last:  newer-than-pf(sb) = st+st = 2          -> vmcnt(2)
        if (sb == 0)
            asm volatile("s_waitcnt vmcnt(3) lgkmcnt(0)\ns_barrier" ::: "memory");
        else if (sb == 1)
            asm volatile("s_waitcnt vmcnt(4) lgkmcnt(0)\ns_barrier" ::: "memory");
        else if (sb + 1 < NSB)
            asm volatile("s_waitcnt vmcnt(5) lgkmcnt(0)\ns_barrier" ::: "memory");
        else
            asm volatile("s_waitcnt vmcnt(2) lgkmcnt(0)\ns_barrier" ::: "memory");

        const char* hrd = (const char*)hist + 16 * qq;
        const float* gp = gi_lds + cb * SB * 3 * D + drow;
        short* hwr = hist + D + drow;

        // gi software pipeline: gi_lds stable all superstep; step s+1's gate inputs load
        // during step s's MFMA+gate phase.
        float gr = gp[0], gz = gp[D], gn = gp[2 * D];

        for (int s = 0; s < SB; ++s) {
            bfx8 b0 = *(const bfx8*)(hrd);
            bfx8 b1 = *(const bfx8*)(hrd + 64);
            bfx8 b2 = *(const bfx8*)(hrd + 128);
            bfx8 b3 = *(const bfx8*)(hrd + 192);
            float grn = 0.f, gzn = 0.f, gnn = 0.f;
            if (s + 1 < SB) {
                grn = gp[3 * D];
                gzn = gp[4 * D];
                gnn = gp[5 * D];
            }

            // 6 independent 4-deep chains interleaved (grouping regresses: round-1 lesson)
            fx4 acc[3][2];
#pragma unroll
            for (int tau = 0; tau < 3; ++tau)
#pragma unroll
                for (int mqi = 0; mqi < 2; ++mqi) {
                    fx4 c0 = (tau == 2) ? bias2[mqi] : zed;
                    c0 = MFMA(a[tau][mqi][0], b0, c0);
                    c0 = MFMA(a[tau][mqi][1], b1, c0);
                    c0 = MFMA(a[tau][mqi][2], b2, c0);
                    c0 = MFMA(a[tau][mqi][3], b3, c0);
                    acc[tau][mqi] = c0;
                }

            float ar = sel4(mqsel ? acc[0][1] : acc[0][0], rsel);
            float az = sel4(mqsel ? acc[1][1] : acc[1][0], rsel);
            float an = sel4(mqsel ? acc[2][1] : acc[2][0], rsel);
            float rr = fast_sigmoid(gr + ar);
            float zz = fast_sigmoid(gz + az);
            float nst = fast_tanh(gn + rr * an);
            h = nst + zz * (h - nst);     // 2-op update
            *hwr = f2bf_bits(h);          // 2 replica lanes, same addr+data: free

            hrd += 256;
            gp += 3 * D;
            hwr += D;
            gr = grn; gz = gzn; gn = gnn;
            asm volatile("s_waitcnt lgkmcnt(0)\ns_barrier" ::: "memory");
        }
    }
    // final flush
    {
        u16x4 hv = *(const u16x4*)(hist + fr * D + fc);
        int orow = (NSB - 1) * SB + fr - 1;
        if (isbf) {
            *(u16x4*)((unsigned short*)out + orow * D + fc) = hv;
        } else {
            float* op = (float*)out + orow * D + fc;
            fx4 f0;
#pragma unroll
            for (int j = 0; j < 4; ++j) f0[j] = bfbits2f(hv[j]);
            *(fx4*)op = f0;
        }
    }
}

extern "C" void kernel_launch(void* const* d_in, const int* in_sizes, int n_in,
                              void* d_out, int out_size, void* d_ws, size_t ws_size,
                              hipStream_t stream) {
    (void)in_sizes; (void)n_in; (void)out_size; (void)ws_size;

    float* w0 = (float*)d_ws;
    int*   flag = (int*)w0;                 // w0[0]
    int*   cnt  = (int*)w0 + 16;            // 128 per-8-row-group counters
    int*   rcnt = (int*)w0 + 160;           // 128 split-row arrival counters
    float* base = w0 + 320;
    float* Xf    = base;                    // 131072
    float* vf    = Xf + 131072;             // 128
    float* whhf  = vf + 128;                // 49152
    float* bihf  = whhf + 49152;            // 384
    float* bhhf  = bihf + 384;              // 384
    float* wihT  = bhhf + 384;              // 98304 (full c-major: [256][384])
    float* q     = wihT + 98304;            // 131072
    float* kT    = q + 131072;              // 131072
    float* gi    = kT + 131072;             // 393216
    float* attMS = gi + 393216;             // 2048  (128 rows x 8 parts x {m,S})
    float* attA  = attMS + 2048;            // 131072 (128 rows x 8 parts x 128)

    qkprep_kernel<<<1604, 256, 0, stream>>>(d_in[0], d_in[1], d_in[2], d_in[3],
                                            d_in[4], d_in[5], d_in[6], d_in[7],
                                            Xf, q, kT, vf, wihT, whhf, bihf, bhhf,
                                            flag, cnt, rcnt);
    fused_kernel<<<1345, 256, 0, stream>>>(q, kT, vf, Xf, wihT, bihf, bhhf,
                                           gi, whhf, d_out, flag, cnt, rcnt,
                                           attMS, attA);
}

// Round 14
// 554.975 us; speedup vs baseline: 1.1126x; 1.1126x over previous
//
#include <hip/hip_runtime.h>
#include <hip/hip_bf16.h>

#define N 1024
#define D 128
#define SB 8           // steps per superstep (gi chunk staged in LDS)
#define NSB (N / SB)

typedef __hip_bfloat16 bf16;
typedef __attribute__((ext_vector_type(8))) short bfx8;    // 8 bf16 (4 VGPRs) MFMA A/B frag
typedef __attribute__((ext_vector_type(4))) float fx4;     // MFMA C/D frag
typedef __attribute__((ext_vector_type(4))) unsigned short u16x4;

__device__ __forceinline__ float b2f(bf16 x) { return __bfloat162float(x); }
__device__ __forceinline__ short f2bf_bits(float x) {
    bf16 b = __float2bfloat16(x);
    return *reinterpret_cast<short*>(&b);
}
__device__ __forceinline__ float bfbits2f(unsigned short u) {
    return __uint_as_float(((unsigned int)u) << 16);
}
__device__ __forceinline__ float fastrcp(float x) { return __builtin_amdgcn_rcpf(x); }

__device__ __forceinline__ float fast_tanh(float x) {
    float e = __expf(2.f * x);
    return 1.f - 2.f * fastrcp(e + 1.f);
}
__device__ __forceinline__ float fast_sigmoid(float x) {
    return fastrcp(1.f + __expf(-x));
}

// dynamic extract from fx4 by r (3 cndmask)
__device__ __forceinline__ float sel4(fx4 v, int r) {
    float x = (r & 1) ? v[1] : v[0];
    float y = (r & 1) ? v[3] : v[2];
    return (r & 2) ? y : x;
}

// async 16B global->LDS (lds base wave-uniform; HW scatters lane i at base+i*16)
__device__ __forceinline__ void async_copy16(const float* g, void* l) {
    __builtin_amdgcn_global_load_lds((const __attribute__((address_space(1))) void*)g,
                                     (__attribute__((address_space(3))) void*)l, 16, 0, 0);
}

// consumer-side: wait until all 8 rows of 8-row group grp are published.
// SPIN-SAFETY (r6/r8 lessons): the ONLY spinner in the whole pipeline is the single GRU
// block; producer blocks never wait on anything (retire-per-unit). No global barriers.
__device__ __forceinline__ void wait_rows(int* cnt, int grp) {
    while (__hip_atomic_load(&cnt[grp], __ATOMIC_ACQUIRE, __HIP_MEMORY_SCOPE_AGENT) < 8)
        __builtin_amdgcn_s_sleep(2);
}

__device__ __forceinline__ float cvt(const void* p, int idx, int isbf) {
    return isbf ? b2f(((const bf16*)p)[idx]) : ((const float*)p)[idx];
}

#define MFMA(A, B, C) __builtin_amdgcn_mfma_f32_16x16x32_bf16((A), (B), (C), 0, 0, 0)

// ---------------- K0: per-block sniff + convert + transpose, all inputs (r4-exact) -----
// Every block sniffs the SAME 1024 samples of X -> identical local decision (no dependency).
// Transposed-weight emission is the key: downstream reads are lane-coalesced. Raw
// per-thread weight-row gathers (r9/r10) and LDS-staged transposes (r13) both lost to it.
__global__ void __launch_bounds__(256) prep_kernel(
        const void* inX, const void* inWq, const void* inWk, const void* inV,
        const void* inWih, const void* inWhh, const void* inBih, const void* inBhh,
        float* __restrict__ Xf, float* __restrict__ WqT, float* __restrict__ WkT,
        float* __restrict__ vf, float* __restrict__ wihT, float* __restrict__ whhf,
        float* __restrict__ bihf, float* __restrict__ bhhf,
        int* __restrict__ flag, int* __restrict__ cnt, int* __restrict__ rcnt) {
    __shared__ int red[256];
    int t = threadIdx.x;
    const unsigned short* xu = (const unsigned short*)inX;
    int c = 0;
#pragma unroll
    for (int k = 0; k < 4; ++k) {
        unsigned short u = xu[2 * (4 * t + k)];
        int e = (u >> 7) & 0xFF;
        c += (e >= 96 && e <= 144) ? 1 : 0;
    }
    red[t] = c;
    __syncthreads();
    for (int st = 128; st > 0; st >>= 1) {
        if (t < st) red[t] += red[t + st];
        __syncthreads();
    }
    int isbf = red[0] > 800;

    if (blockIdx.x == 0) {
        if (t == 0) *flag = isbf;
        if (t < 128) { cnt[t] = 0; rcnt[t] = 0; }
    }

    int id = blockIdx.x * 256 + t;
    if (id < 131072) {
        Xf[id] = cvt(inX, id, isbf);
    } else if (id < 147456) {
        int k = id - 131072; int cc = k >> 7, d = k & 127;
        WqT[k] = cvt(inWq, d * 128 + cc, isbf);
    } else if (id < 163840) {
        int k = id - 147456; int cc = k >> 7, d = k & 127;
        WkT[k] = cvt(inWk, d * 128 + cc, isbf);
    } else if (id < 163968) {
        vf[id - 163840] = cvt(inV, id - 163840, isbf);
    } else if (id < 262272) {
        int k = id - 163968; int cc = k / 384, o = k - cc * 384;
        wihT[k] = cvt(inWih, o * 256 + cc, isbf);
    } else if (id < 311424) {
        whhf[id - 262272] = cvt(inWhh, id - 262272, isbf);
    } else if (id < 311808) {
        bihf[id - 311424] = cvt(inBih, id - 311424, isbf);
    } else if (id < 312192) {
        bhhf[id - 311808] = cvt(inBhh, id - 311808, isbf);
    }
}

// ---------------- K1: q, kT, gi_x = X@wih_xT (r4-exact: 1024 thin blocks, coalesced) ----
__global__ void __launch_bounds__(256) qk_gix_kernel(
        const float* __restrict__ X, const float* __restrict__ WqT,
        const float* __restrict__ WkT, const float* __restrict__ wihT,
        float* __restrict__ q, float* __restrict__ kT, float* __restrict__ gix) {
    int i = blockIdx.x, t = threadIdx.x;
    __shared__ float xs[D];
    if (t < D) xs[t] = X[i * D + t];
    __syncthreads();
    int d = t & 127;
    const float* WT = (t < 128) ? WqT : WkT;
    float acc = 0.f;
#pragma unroll 8
    for (int cc = 0; cc < D; ++cc) acc += xs[cc] * WT[cc * D + d];
    if (t < 128) q[i * D + d] = acc;
    else         kT[d * N + i] = acc;

    for (int o = t; o < 3 * D; o += 256) {
        float a2 = 0.f;
#pragma unroll 8
        for (int cc = 0; cc < D; ++cc) a2 += xs[cc] * wihT[cc * 384 + o];
        gix[i * 384 + o] = a2;
    }
}

// ---------------- K2: fused producer/consumer (r12-exact, measured 470.6us) -------------
// block 0: GRU (setprio 2). blocks 1..256: rows 0-31 split 8-way; 257..448: rows 32-127
// split 2-way; 449..1344: rows 128-1023 whole. Split parts write online-softmax partials
// (m,S,A) to ws; last-arriving part combines + Phase D + publishes cnt[row/8].
// LDS union: GRU needs 2*8*384*4 + 9*128*2 = 26880 B; attn needs 6656 B.
// ALL hot-path inputs are pre-converted floats (r9 lesson: inline cvt costs +37us).
// Phase A/B use STATIC 4-iter unrolls so sj[] is compile-time-indexed (registers, not
// scratch — rule #20; r12: −30% attn wave-time, fused 502->471).
// NOTE: do NOT set a min-waves launch bound here — capping VGPRs below ~130 spills the
// GRU's 96 resident weight VGPRs to scratch (round-3 catastrophe: 617 -> 1676 us).
__global__ void __launch_bounds__(256, 1) fused_kernel(
        const float* __restrict__ q, const float* __restrict__ kT,
        const float* __restrict__ v, const float* __restrict__ X,
        const float* __restrict__ wihTa, const float* __restrict__ b_ih,
        const float* __restrict__ b_hh, const float* __restrict__ gix,
        float* __restrict__ gi, const float* __restrict__ w_hh,
        void* __restrict__ out, const int* __restrict__ flag,
        int* __restrict__ cnt, int* __restrict__ rcnt,
        float* __restrict__ attMS, float* __restrict__ attA) {
    __shared__ __align__(16) char smem[2 * SB * 3 * D * 4 + (SB + 1) * D * 2];  // 26880 B
    int t = threadIdx.x;

    if (blockIdx.x != 0) {
        // =================== attention row (full or partial) ===================
        int b = blockIdx.x - 1;
        int i, P, p;
        if (b < 256)      { i = b >> 3;            P = 8; p = b & 7; }
        else if (b < 448) { int e = b - 256; i = 32 + (e >> 1); P = 2; p = e & 1; }
        else              { i = 128 + (b - 448);   P = 1; p = 0; }

        float* qs   = (float*)smem;        // D
        float* vs   = qs + D;              // D
        float* al   = vs + D;              // D
        float* wrow = al + D;              // up to 1024
        float* red  = wrow + N;            // 256

        int len = (N - i + P - 1) / P;
        int j0 = i + p * len;
        int j1 = min(j0 + len, N);

        if (t < D) { qs[t] = q[i * D + t]; vs[t] = v[t]; }
        __syncthreads();

        // Phase A: scores over [j0, j1) — static 4-iter unroll (sj in registers,
        // 4 independent kT-load/tanh streams in flight). Max chunk 896 -> 4 iters cover.
        float sj[4];
        float m = -1e30f;
#pragma unroll
        for (int it = 0; it < 4; ++it) {
            int j = j0 + t + it * 256;
            float s = -1e30f;
            if (j < j1) {
                s = 0.f;
#pragma unroll 8
                for (int dd = 0; dd < D; ++dd)
                    s += vs[dd] * fast_tanh(qs[dd] + kT[dd * N + j]);
            }
            sj[it] = s;
            m = fmaxf(m, s);
        }
        red[t] = m;
        __syncthreads();
        for (int st = 128; st > 0; st >>= 1) {
            if (t < st) red[t] = fmaxf(red[t], red[t + st]);
            __syncthreads();
        }
        m = red[0];
        __syncthreads();
        // Phase B: exp + local sum (same static indexing)
        float lsum = 0.f;
#pragma unroll
        for (int it = 0; it < 4; ++it) {
            int j = j0 + t + it * 256;
            if (j < j1) {
                float pe = __expf(sj[it] - m);
                wrow[j - j0] = pe;
                lsum += pe;
            }
        }
        red[t] = lsum;
        __syncthreads();
        for (int st = 128; st > 0; st >>= 1) {
            if (t < st) red[t] += red[t + st];
            __syncthreads();
        }
        float S = red[0];
        __syncthreads();
        // Phase C: unnormalized A[d] over chunk (2-way j split); unroll 4 for load ILP
        int d = t & 127, half = t >> 7;
        float acc = 0.f;
        int cl = j1 - j0;
#pragma unroll 4
        for (int jj = half; jj < cl; jj += 2) acc += wrow[jj] * X[(j0 + jj) * D + d];
        if (half) red[d] = acc;
        __syncthreads();
        if (!half) al[d] = acc + red[d];
        __syncthreads();

        if (P > 1) {
            // write partials, last-arriver combines
            if (t < D) attA[(i * 8 + p) * D + t] = al[t];
            if (t == 0) { attMS[(i * 8 + p) * 2] = m; attMS[(i * 8 + p) * 2 + 1] = S; }
            __syncthreads();
            if (t == 0) {
                __threadfence();
                int arr = __hip_atomic_fetch_add(&rcnt[i], 1, __ATOMIC_ACQ_REL,
                                                 __HIP_MEMORY_SCOPE_AGENT);
                ((int*)red)[0] = arr;
            }
            __syncthreads();
            int arr = ((int*)red)[0];
            if (arr != P - 1) return;   // uniform per block
            // finisher: combine partials
            if (t < D) {
                float M = -1e30f;
                for (int pp = 0; pp < P; ++pp) M = fmaxf(M, attMS[(i * 8 + pp) * 2]);
                float Ssum = 0.f, av = 0.f;
                for (int pp = 0; pp < P; ++pp) {
                    float wp = __expf(attMS[(i * 8 + pp) * 2] - M);
                    Ssum += attMS[(i * 8 + pp) * 2 + 1] * wp;
                    av += attA[(i * 8 + pp) * D + t] * wp;
                }
                al[t] = av * fastrcp(Ssum);
            }
            __syncthreads();
        } else {
            float inv = fastrcp(S);
            if (t < D) al[t] *= inv;
            __syncthreads();
        }

        // Phase D: att-part only (X-part precomputed as gix); fold b_hh for r,z gates.
        // wihTa is c-major att-half -> wt[cc*384] coalesced across o (proven pattern).
        for (int o = t; o < 3 * D; o += 256) {
            float a2 = b_ih[o] + ((o < 2 * D) ? b_hh[o] : 0.f) + gix[i * 384 + o];
            const float* wt = wihTa + o;
#pragma unroll 8
            for (int cc = 0; cc < D; ++cc) a2 += al[cc] * wt[cc * 384];
            gi[i * 3 * D + o] = a2;
        }
        __syncthreads();
        if (t == 0) {
            __threadfence();
            __hip_atomic_fetch_add(&cnt[i >> 3], 1, __ATOMIC_RELEASE, __HIP_MEMORY_SCOPE_AGENT);
        }
        return;
    }

    // =================== GRU (1 block, serial over N steps) ===================
    __builtin_amdgcn_s_setprio(2);
    float* gi_lds = (float*)smem;                           // [2][SB][3D]
    short* hist   = (short*)(smem + 2 * SB * 3 * D * 4);    // [SB+1][D]
    int w = t >> 6;
    int l = t & 63;
    int qq = l >> 4;
    int nn = l & 15;
    int isbf = *flag;

    // A-frags: a[tau][mqi][kc]; A[m=nn][k=32kc+8q+j]  (96 resident VGPRs — must NOT spill)
    bfx8 a[3][2][4];
#pragma unroll
    for (int tau = 0; tau < 3; ++tau)
#pragma unroll
        for (int mqi = 0; mqi < 2; ++mqi)
#pragma unroll
            for (int kc = 0; kc < 4; ++kc) {
                int row = 128 * tau + 16 * (2 * w + mqi) + nn;
                int k0 = 32 * kc + 8 * qq;
#pragma unroll
                for (int j = 0; j < 8; ++j)
                    a[tau][mqi][kc][j] = f2bf_bits(w_hh[row * D + k0 + j]);
            }
    // n-gate bias only (r,z biases folded into gi by the producer)
    fx4 bias2[2];
#pragma unroll
    for (int mqi = 0; mqi < 2; ++mqi)
#pragma unroll
        for (int r = 0; r < 4; ++r)
            bias2[mqi][r] = b_hh[2 * D + 16 * (2 * w + mqi) + 4 * qq + r];
    const fx4 zed = {0.f, 0.f, 0.f, 0.f};

    int rsel = l & 3;
    int mqsel = (l >> 3) & 1;
    int drow = 32 * w + 16 * mqsel + 4 * qq + rsel;
    float h = 0.f;

    int fr = 1 + (t >> 5);      // 1..8
    int fc = (t & 31) * 4;      // 0..124

    // wait for first 8 rows, prime superstep-0 staging (3 copies/wave)
    wait_rows(cnt, 0);
    {
        const float* src = gi;
        for (int mm = 0; mm < 3; ++mm) {
            int off = (w * 3 + mm) * 256;
            async_copy16(src + off + (l << 2), smem + off * 4);
        }
    }

    for (int sb = 0; sb < NSB; ++sb) {
        int cb = sb & 1;
        u16x4 hv = {0, 0, 0, 0};
        int hcopy = 0;
        if (sb > 0) {
            hv = *(const u16x4*)(hist + fr * D + fc);
            if (t < 64) hcopy = ((const int*)(hist + SB * D))[t];
        }
        // prefetch sb+1 FIRST (counted vmcnt leaves stores in flight)
        if (sb + 1 < NSB) {
            wait_rows(cnt, sb + 1);
            const float* src = gi + (size_t)(sb + 1) * SB * 3 * D;
            char* dst = smem + (cb ^ 1) * SB * 3 * D * 4;
            for (int mm = 0; mm < 3; ++mm) {
                int off = (w * 3 + mm) * 256;
                async_copy16(src + off + (l << 2), dst + off * 4);
            }
        }
        // output stores for superstep sb-1 (1 store/thread)
        if (sb > 0) {
            int orow = (sb - 1) * SB + fr - 1;
            if (isbf) {
                *(u16x4*)((unsigned short*)out + orow * D + fc) = hv;
            } else {
                float* op = (float*)out + orow * D + fc;
                fx4 f0;
#pragma unroll
                for (int j = 0; j < 4; ++j) f0[j] = bfbits2f(hv[j]);
                *(fx4*)op = f0;
            }
        }
        if (t < 64) ((int*)hist)[t] = (sb == 0) ? 0 : hcopy;

        // Counted vmcnt (in-order retirement); pf=3 copies, st=1 store per thread:
        //   sb==0: newer-than-pf(0) = pf(1)=3             -> vmcnt(3)
        //   sb==1: newer-than-pf(1) = pf(2)+st = 4        -> vmcnt(4)
        //   mid:   newer-than-pf(sb) = st+pf+st = 5       -> vmcnt(5)
        //   last:  newer-than-pf(sb) = st+st = 2          -> vmcnt(2)
        if (sb == 0)
            asm volatile("s_waitcnt vmcnt(3) lgkmcnt(0)\ns_barrier" ::: "memory");
        else if (sb == 1)
            asm volatile("s_waitcnt vmcnt(4) lgkmcnt(0)\ns_barrier" ::: "memory");
        else if (sb + 1 < NSB)
            asm volatile("s_waitcnt vmcnt(5) lgkmcnt(0)\ns_barrier" ::: "memory");
        else
            asm volatile("s_waitcnt vmcnt(2) lgkmcnt(0)\ns_barrier" ::: "memory");

        const char* hrd = (const char*)hist + 16 * qq;
        const float* gp = gi_lds + cb * SB * 3 * D + drow;
        short* hwr = hist + D + drow;

        // gi software pipeline: gi_lds stable all superstep; step s+1's gate inputs load
        // during step s's MFMA+gate phase.
        float gr = gp[0], gz = gp[D], gn = gp[2 * D];

        for (int s = 0; s < SB; ++s) {
            bfx8 b0 = *(const bfx8*)(hrd);
            bfx8 b1 = *(const bfx8*)(hrd + 64);
            bfx8 b2 = *(const bfx8*)(hrd + 128);
            bfx8 b3 = *(const bfx8*)(hrd + 192);
            float grn = 0.f, gzn = 0.f, gnn = 0.f;
            if (s + 1 < SB) {
                grn = gp[3 * D];
                gzn = gp[4 * D];
                gnn = gp[5 * D];
            }

            // 6 independent 4-deep chains interleaved (grouping regresses: round-1 lesson)
            fx4 acc[3][2];
#pragma unroll
            for (int tau = 0; tau < 3; ++tau)
#pragma unroll
                for (int mqi = 0; mqi < 2; ++mqi) {
                    fx4 c0 = (tau == 2) ? bias2[mqi] : zed;
                    c0 = MFMA(a[tau][mqi][0], b0, c0);
                    c0 = MFMA(a[tau][mqi][1], b1, c0);
                    c0 = MFMA(a[tau][mqi][2], b2, c0);
                    c0 = MFMA(a[tau][mqi][3], b3, c0);
                    acc[tau][mqi] = c0;
                }

            float ar = sel4(mqsel ? acc[0][1] : acc[0][0], rsel);
            float az = sel4(mqsel ? acc[1][1] : acc[1][0], rsel);
            float an = sel4(mqsel ? acc[2][1] : acc[2][0], rsel);
            float rr = fast_sigmoid(gr + ar);
            float zz = fast_sigmoid(gz + az);
            float nst = fast_tanh(gn + rr * an);
            h = nst + zz * (h - nst);     // 2-op update
            *hwr = f2bf_bits(h);          // 2 replica lanes, same addr+data: free

            hrd += 256;
            gp += 3 * D;
            hwr += D;
            gr = grn; gz = gzn; gn = gnn;
            asm volatile("s_waitcnt lgkmcnt(0)\ns_barrier" ::: "memory");
        }
    }
    // final flush
    {
        u16x4 hv = *(const u16x4*)(hist + fr * D + fc);
        int orow = (NSB - 1) * SB + fr - 1;
        if (isbf) {
            *(u16x4*)((unsigned short*)out + orow * D + fc) = hv;
        } else {
            float* op = (float*)out + orow * D + fc;
            fx4 f0;
#pragma unroll
            for (int j = 0; j < 4; ++j) f0[j] = bfbits2f(hv[j]);
            *(fx4*)op = f0;
        }
    }
}

extern "C" void kernel_launch(void* const* d_in, const int* in_sizes, int n_in,
                              void* d_out, int out_size, void* d_ws, size_t ws_size,
                              hipStream_t stream) {
    (void)in_sizes; (void)n_in; (void)out_size; (void)ws_size;

    float* w0 = (float*)d_ws;
    int*   flag = (int*)w0;                 // w0[0]
    int*   cnt  = (int*)w0 + 16;            // 128 per-8-row-group counters
    int*   rcnt = (int*)w0 + 160;           // 128 split-row arrival counters
    float* base = w0 + 320;
    float* Xf    = base;                    // 131072
    float* vf    = Xf + 131072;             // 128
    float* whhf  = vf + 128;                // 49152
    float* bihf  = whhf + 49152;            // 384
    float* bhhf  = bihf + 384;              // 384
    float* WqT   = bhhf + 384;              // 16384
    float* WkT   = WqT + 16384;             // 16384
    float* wihT  = WkT + 16384;             // 98304 (c-major: [256][384])
    float* q     = wihT + 98304;            // 131072
    float* kT    = q + 131072;              // 131072
    float* gix   = kT + 131072;             // 393216
    float* gi    = gix + 393216;            // 393216
    float* attMS = gi + 393216;             // 2048  (128 rows x 8 parts x {m,S})
    float* attA  = attMS + 2048;            // 131072 (128 rows x 8 parts x 128)

    prep_kernel<<<1220, 256, 0, stream>>>(d_in[0], d_in[1], d_in[2], d_in[3],
                                          d_in[4], d_in[5], d_in[6], d_in[7],
                                          Xf, WqT, WkT, vf, wihT, whhf, bihf, bhhf,
                                          flag, cnt, rcnt);
    qk_gix_kernel<<<N, 256, 0, stream>>>(Xf, WqT, WkT, wihT, q, kT, gix);
    fused_kernel<<<1345, 256, 0, stream>>>(q, kT, vf, Xf, wihT + 128 * 384, bihf, bhhf,
                                           gix, gi, whhf, d_out, flag, cnt, rcnt,
                                           attMS, attA);
}